// Round 8
// baseline (187.559 us; speedup 1.0000x reference)
//
#include <hip/hip_runtime.h>

#define B_ 2
#define N_ 10000
#define E_ 150000
#define C_ 256
#define M_EDGE (B_*E_)   // 300000
#define M_NODE (B_*N_)   // 20000
#define ED_CAP (M_EDGE + 3*M_NODE + 64)   // padded CSR capacity + tail slack
#define NW_ 8192                           // k_agg streams (2048 blocks x 4)
#define EPS_ 1e-5f

typedef unsigned short u16;
typedef unsigned int   u32;
typedef __attribute__((ext_vector_type(8))) __bf16 bf16x8;
typedef __attribute__((ext_vector_type(4))) float  f32x4;
typedef _Float16 h2 __attribute__((ext_vector_type(2)));

__device__ __forceinline__ u16 f2bf(float x) {
  union { float f; u32 u; } v; v.f = x;
  u32 r = v.u + 0x7FFFu + ((v.u >> 16) & 1u);   // RNE
  return (u16)(r >> 16);
}
__device__ __forceinline__ float bf2f(u16 x) {
  union { u32 u; float f; } v; v.u = ((u32)x) << 16; return v.f;
}
__device__ __forceinline__ u16 f2h(float x) {
  _Float16 h = (_Float16)x;
  union { _Float16 h; u16 u; } v; v.h = h; return v.u;
}
__device__ __forceinline__ h2 u2h2(u32 x) {
  union { u32 u; h2 h; } v; v.u = x; return v.h;
}
__device__ __forceinline__ u32 h22u(h2 x) {
  union { h2 h; u32 u; } v; v.h = x; return v.u;
}

__device__ __forceinline__ void async16(void* lds, const void* g) {
  __builtin_amdgcn_global_load_lds(
      (const __attribute__((address_space(1))) void*)g,
      (__attribute__((address_space(3))) void*)lds, 16, 0, 0);
}

// ---------------- init: zero counts + stats ----------------
__global__ void k_init(int* __restrict__ counts, float* __restrict__ stats) {
  int i = blockIdx.x * 256 + threadIdx.x;
  if (i < M_NODE) counts[i] = 0;
  if (i < 1024) stats[i] = 0.f;
}

// ---------------- features [B][C][N] f32 -> vf [B][N][C] bf16 ----------------
__global__ void k_transpose_feat(const float* __restrict__ f, u16* __restrict__ vf) {
  __shared__ float tile[32][33];
  int tx = threadIdx.x & 31, ty = threadIdx.x >> 5;
  int b = blockIdx.z, c0 = blockIdx.y * 32, n0 = blockIdx.x * 32;
  #pragma unroll
  for (int i = 0; i < 4; i++) {
    int c = c0 + ty + i*8, n = n0 + tx;
    tile[ty + i*8][tx] = (n < N_) ? f[((size_t)(b*C_ + c))*N_ + n] : 0.f;
  }
  __syncthreads();
  #pragma unroll
  for (int i = 0; i < 4; i++) {
    int n = n0 + ty + i*8, c = c0 + tx;
    if (n < N_) vf[((size_t)(b*N_ + n))*C_ + c] = f2bf(tile[tx][ty + i*8]);
  }
}

// ---------------- W_e[0:256][:], W_u -> transposed bf16 [Cout][K] ----------------
__global__ void k_transpose_w(const float* __restrict__ We, const float* __restrict__ Wu,
                              u16* __restrict__ WeT, u16* __restrict__ WuT) {
  __shared__ float tile[32][33];
  const float* src = blockIdx.z ? Wu : We;
  u16* dst = blockIdx.z ? WuT : WeT;
  int tx = threadIdx.x & 31, ty = threadIdx.x >> 5;
  int r0 = blockIdx.y * 32, c0 = blockIdx.x * 32;
  #pragma unroll
  for (int i = 0; i < 4; i++)
    tile[ty + i*8][tx] = src[(size_t)(r0 + ty + i*8)*C_ + c0 + tx];
  __syncthreads();
  #pragma unroll
  for (int i = 0; i < 4; i++)
    dst[(size_t)(c0 + ty + i*8)*C_ + r0 + tx] = f2bf(tile[tx][ty + i*8]);
}

// ---------------- histogram of dst ----------------
__global__ void k_hist(const int* __restrict__ edges, int* __restrict__ counts) {
  int i = blockIdx.x * 256 + threadIdx.x;
  if (i >= M_EDGE) return;
  int b = (i >= E_) ? 1 : 0;
  int e = i - b * E_;
  int d = edges[(size_t)(b*2 + 1)*E_ + e];
  atomicAdd(&counts[b*N_ + d], 1);
}

// ---------------- exclusive scan of PADDED counts (single block) ----------------
__global__ __launch_bounds__(1024)
void k_scan(const int* __restrict__ counts, int* __restrict__ offs, int* __restrict__ cursor) {
  __shared__ int part[1024];
  int t = threadIdx.x;
  int base = t * 20;
  int vals[20];
  if (t < 1000) {
    #pragma unroll
    for (int j = 0; j < 5; j++)
      *(int4*)&vals[j*4] = *(const int4*)&counts[base + j*4];
  } else {
    #pragma unroll
    for (int i = 0; i < 20; i++) vals[i] = 0;
  }
  int local[20];
  int s = 0;
  #pragma unroll
  for (int i = 0; i < 20; i++) {
    int pv = (vals[i] + 3) & ~3;          // pad each node to multiple of 4
    local[i] = s; s += pv;
  }
  part[t] = s;
  __syncthreads();
  for (int d = 1; d < 1024; d <<= 1) {
    int v = (t >= d) ? part[t - d] : 0;
    __syncthreads();
    part[t] += v;
    __syncthreads();
  }
  int excl = (t == 0) ? 0 : part[t - 1];
  if (t < 1000) {
    #pragma unroll
    for (int j = 0; j < 5; j++) {
      int4 o;
      o.x = excl + local[j*4 + 0];
      o.y = excl + local[j*4 + 1];
      o.z = excl + local[j*4 + 2];
      o.w = excl + local[j*4 + 3];
      *(int4*)&offs[base + j*4]   = o;
      *(int4*)&cursor[base + j*4] = o;
    }
  }
  if (t == 1023) offs[M_NODE] = part[1023];   // total padded size
}

// ---------------- scatter edges into padded CSR slots (packed 8B records) ----------------
// rec.x = f16(dx) | f16(dy)<<16 ; rec.y = f16(dz) | src_node<<16
__global__ void k_scatter(const int* __restrict__ edges, const float* __restrict__ xyz,
                          int* __restrict__ cursor, uint2* __restrict__ ed) {
  int i = blockIdx.x * 256 + threadIdx.x;
  if (i >= M_EDGE) return;
  int b = (i >= E_) ? 1 : 0;
  int e = i - b * E_;
  int s = edges[(size_t)(b*2 + 0)*E_ + e];
  int d = edges[(size_t)(b*2 + 1)*E_ + e];
  const float* ps = xyz + ((size_t)(b*N_ + s))*3;
  const float* pd = xyz + ((size_t)(b*N_ + d))*3;
  int pos = atomicAdd(&cursor[b*N_ + d], 1);
  u32 rx = (u32)f2h(ps[0]-pd[0]) | ((u32)f2h(ps[1]-pd[1]) << 16);
  u32 ry = (u32)f2h(ps[2]-pd[2]) | ((u32)(b*N_ + s) << 16);
  ed[pos] = make_uint2(rx, ry);
}

// ------- pad dup fill + tail fill + nodeInfo + waveStart table -------
// nodeInfo[n] = (paddedEnd << 10) | cnt
// waveStart[w] = first node whose padded segment starts >= w*SPW
__global__ void k_pad(const int* __restrict__ offs, const int* __restrict__ counts,
                      uint2* __restrict__ ed, u32* __restrict__ nodeInfo,
                      int* __restrict__ waveStart) {
  int i = blockIdx.x * 256 + threadIdx.x;
  const int T = offs[M_NODE];
  const int SPW = (T + NW_ - 1) / NW_;
  if (i < M_NODE) {
    int s = offs[i], e = offs[i+1];
    int cnt = counts[i];
    if (cnt > 0) {
      int pad = e - (s + cnt);
      if (pad) {
        uint2 f = ed[s];
        for (int k = 0; k < pad; k++) ed[s + cnt + k] = f;
      }
    }
    nodeInfo[i] = ((u32)e << 10) | (u32)cnt;
    int lo = (i == 0) ? 0 : offs[i-1] + 1;
    int wlo = (lo + SPW - 1) / SPW;
    int whi = offs[i] / SPW;
    for (int w = wlo; w <= whi && w <= NW_; w++) waveStart[w] = i;
  }
  if (i == M_NODE) {
    nodeInfo[M_NODE]   = ((u32)T << 10);
    nodeInfo[M_NODE+1] = ((u32)T << 10);
    int lo = offs[M_NODE-1] + 1;
    int wlo = (lo + SPW - 1) / SPW;
    if (wlo < 0) wlo = 0;
    for (int w = wlo; w <= NW_; w++) waveStart[w] = M_NODE;
  }
  int pos = T + i;
  if (pos < ED_CAP) ed[pos] = make_uint2(0u, 0u);   // tail: si=0, never stats-counted
}

// ---------------- z GEMM: z = vf @ We[0:256] + be (fp16 out) ----------------
__global__ __launch_bounds__(256)
void k_zgemm(const u16* __restrict__ A, const u16* __restrict__ WeT,
             const float* __restrict__ be, u16* __restrict__ zh)
{
  __shared__ __align__(16) u16 As[128*32];
  __shared__ __align__(16) u16 Bs[128*32];
  const int t  = threadIdx.x;
  const int n0 = blockIdx.x * 128;
  const int mb = blockIdx.y * 128;

  int r0 = mb + (t >> 2);      if (r0 >= M_NODE) r0 = 0;
  int r1 = mb + 64 + (t >> 2); if (r1 >= M_NODE) r1 = 0;
  const int ak = (((t & 3) ^ ((t >> 3) & 3)) << 3);
  const u16* asrc0 = A + (size_t)r0 * C_ + ak;
  const u16* asrc1 = A + (size_t)r1 * C_ + ak;
  const u16* bsrc0 = WeT + (size_t)(n0 + (t >> 2)) * C_ + ak;
  const u16* bsrc1 = WeT + (size_t)(n0 + 64 + (t >> 2)) * C_ + ak;

  const f32x4 zero = {0.f, 0.f, 0.f, 0.f};
  f32x4 acc[4][4];
  #pragma unroll
  for (int m = 0; m < 4; m++)
    #pragma unroll
    for (int n = 0; n < 4; n++) acc[m][n] = zero;

  const int lane = t & 63, wave = t >> 6;
  const int wr = wave >> 1, wc = wave & 1;
  const int lr = lane & 15, lch = lane >> 4;
  const int swz = (lr >> 1) & 3;

  for (int kk = 0; kk < 8; kk++) {
    const int k0 = kk * 32;
    async16(&As[t*8],        asrc0 + k0);
    async16(&As[(t+256)*8],  asrc1 + k0);
    async16(&Bs[t*8],        bsrc0 + k0);
    async16(&Bs[(t+256)*8],  bsrc1 + k0);
    __syncthreads();
    bf16x8 a[4], b[4];
    #pragma unroll
    for (int m = 0; m < 4; m++)
      a[m] = *(const bf16x8*)&As[(wr*64 + m*16 + lr)*32 + ((lch ^ swz) << 3)];
    #pragma unroll
    for (int n = 0; n < 4; n++)
      b[n] = *(const bf16x8*)&Bs[(wc*64 + n*16 + lr)*32 + ((lch ^ swz) << 3)];
    #pragma unroll
    for (int m = 0; m < 4; m++)
      #pragma unroll
      for (int n = 0; n < 4; n++)
        acc[m][n] = __builtin_amdgcn_mfma_f32_16x16x32_bf16(a[m], b[n], acc[m][n], 0, 0, 0);
    __syncthreads();
  }

  int gc[4]; float bias[4];
  #pragma unroll
  for (int n = 0; n < 4; n++) { int c = n0 + wc*64 + n*16 + lr; gc[n] = c; bias[n] = be[c]; }
  #pragma unroll
  for (int m = 0; m < 4; m++) {
    #pragma unroll
    for (int j = 0; j < 4; j++) {
      int r = mb + wr*64 + m*16 + lch*4 + j;
      if (r < M_NODE) {
        #pragma unroll
        for (int n = 0; n < 4; n++)
          zh[(size_t)r * C_ + gc[n]] = f2h(acc[m][n][j] + bias[n]);
      }
    }
  }
}

// -------- aggregation: channel-split, 4-phase pipeline (records 4 ahead, z 2 ahead) --------
__global__ __launch_bounds__(512)
void k_agg(const u16* __restrict__ zh, const uint2* __restrict__ ed,
           const int* __restrict__ offs, const u32* __restrict__ nodeInfo,
           const int* __restrict__ waveStart,
           const float* __restrict__ We, const float* __restrict__ ge,
           u32* __restrict__ aggh, float* __restrict__ esum, float* __restrict__ esumsq)
{
  const int tid  = threadIdx.x;
  const int lane = tid & 63;
  const int wave = __builtin_amdgcn_readfirstlane(tid >> 6);   // 0..7, SGPR
  const int half = wave & 1;
  const int c0   = half * 128 + lane * 2;                      // 2 channels per lane
  h2 w0 = h2{(_Float16)We[256*C_ + c0], (_Float16)We[256*C_ + c0 + 1]};
  h2 w1 = h2{(_Float16)We[257*C_ + c0], (_Float16)We[257*C_ + c0 + 1]};
  h2 w2 = h2{(_Float16)We[258*C_ + c0], (_Float16)We[258*C_ + c0 + 1]};
  const float ge0 = ge[c0], ge1 = ge[c0 + 1];
  const u16* zp = zh + c0;

  float ps0 = 0.f, ps1 = 0.f, pq0 = 0.f, pq1 = 0.f;

  const int wid  = blockIdx.x * 4 + (wave >> 1);   // stream id, 8192 total
  int cur        = __builtin_amdgcn_readfirstlane(waveStart[wid]);
  const int nEnd = __builtin_amdgcn_readfirstlane(waveStart[wid + 1]);

  const h2 MXI = h2{(_Float16)-1.f, (_Float16)-1.f};
  const h2 MNI = h2{(_Float16)65504.f, (_Float16)65504.f};

  if (cur < nEnd) {
    const int uBeg = __builtin_amdgcn_readfirstlane(offs[cur]);
    const int uEnd = __builtin_amdgcn_readfirstlane(offs[nEnd]);
    if (uEnd > uBeg) {
      // skip leading empty nodes (zero padded length)
      u32 info = nodeInfo[cur];
      while ((int)(info >> 10) == uBeg) { cur++; info = nodeInfo[cur]; }
      int curEnd   = (int)(info >> 10);
      int vE       = uBeg + (int)(info & 1023u);
      u32 nextInfo = nodeInfo[cur + 1];

      h2 mx = MXI, mn = MNI;
      const int nc = (uEnd - uBeg) >> 2;

      // buffers: records (stream-uniform) 4 chunks ahead; z issued 2 chunks ahead
      u32 Rx[4][4], Ry[4][4], Z[4][4];

#define LOADR(BUF, CI) { \
      const uint2* _p = ed + (uBeg + (CI)*4); \
      uint2 _r0 = _p[0], _r1 = _p[1], _r2 = _p[2], _r3 = _p[3]; \
      Rx[BUF][0] = _r0.x; Ry[BUF][0] = _r0.y; \
      Rx[BUF][1] = _r1.x; Ry[BUF][1] = _r1.y; \
      Rx[BUF][2] = _r2.x; Ry[BUF][2] = _r2.y; \
      Rx[BUF][3] = _r3.x; Ry[BUF][3] = _r3.y; }

#define ISSUEZ(ZB, RB) { \
      Z[ZB][0] = *(const u32*)(zp + ((size_t)(Ry[RB][0] >> 16) << 8)); \
      Z[ZB][1] = *(const u32*)(zp + ((size_t)(Ry[RB][1] >> 16) << 8)); \
      Z[ZB][2] = *(const u32*)(zp + ((size_t)(Ry[RB][2] >> 16) << 8)); \
      Z[ZB][3] = *(const u32*)(zp + ((size_t)(Ry[RB][3] >> 16) << 8)); }

      auto flushNode = [&](int node) {
        h2 s;
        s.x = (ge0 >= 0.f) ? mx.x : mn.x;
        s.y = (ge1 >= 0.f) ? mx.y : mn.y;
        aggh[(size_t)node * 128 + half * 64 + lane] = h22u(s);
      };

#define PROC(CI, RB, ZB) { \
      const int slot = uBeg + (CI)*4; \
      if (slot == curEnd) { \
        flushNode(cur); \
        mx = MXI; mn = MNI; \
        cur++; \
        u32 inf = nextInfo; \
        while ((int)(inf >> 10) == curEnd) { cur++; inf = nodeInfo[cur]; } \
        vE = curEnd + (int)(inf & 1023u); \
        curEnd = (int)(inf >> 10); \
        nextInfo = nodeInfo[cur + 1]; \
      } \
      _Pragma("unroll") \
      for (int k = 0; k < 4; k++) { \
        u32 rx = Rx[RB][k], ry = Ry[RB][k]; \
        h2 dxx = u2h2((rx & 0xffffu) | (rx << 16)); \
        h2 dyy = u2h2((rx >> 16) | (rx & 0xffff0000u)); \
        h2 dzz = u2h2((ry & 0xffffu) | (ry << 16)); \
        h2 y = dxx*w0 + (dyy*w1 + (dzz*w2 + u2h2(Z[ZB][k]))); \
        const h2 zero2 = h2{(_Float16)0.f, (_Float16)0.f}; \
        y = __builtin_elementwise_max(y, zero2); \
        mx = __builtin_elementwise_max(mx, y); \
        mn = __builtin_elementwise_min(mn, y); \
        if (slot + k < vE) { \
          float f0 = (float)y.x, f1 = (float)y.y; \
          ps0 += f0; pq0 = fmaf(f0, f0, pq0); \
          ps1 += f1; pq1 = fmaf(f1, f1, pq1); \
        } \
      } }

      // prologue: records for chunks 0..3, z for chunks 0..1
      LOADR(0, 0) LOADR(1, 1) LOADR(2, 2) LOADR(3, 3)
      ISSUEZ(0, 0) ISSUEZ(1, 1)

      for (int i = 0; i < nc; i += 4) {
        { ISSUEZ(2, 2) PROC(i + 0, 0, 0) LOADR(0, i + 4) }
        if (i + 1 < nc) { ISSUEZ(3, 3) PROC(i + 1, 1, 1) LOADR(1, i + 5) }
        if (i + 2 < nc) { ISSUEZ(0, 0) PROC(i + 2, 2, 2) LOADR(2, i + 6) }
        if (i + 3 < nc) { ISSUEZ(1, 1) PROC(i + 3, 3, 3) LOADR(3, i + 7) }
      }
      flushNode(cur);
#undef LOADR
#undef ISSUEZ
#undef PROC
    }
  }

  // block-level stats reduction: wave w covers channels [ (w&1)*128, +128 )
  __shared__ float red[8][256];
  red[wave][c0]     = ps0;
  red[wave][c0 + 1] = ps1;
  __syncthreads();
  if (tid < 256) {
    int base = (tid >= 128) ? 1 : 0;
    float s = red[base][tid] + red[base+2][tid] + red[base+4][tid] + red[base+6][tid];
    atomicAdd(&esum[tid], s);
  }
  __syncthreads();
  red[wave][c0]     = pq0;
  red[wave][c0 + 1] = pq1;
  __syncthreads();
  if (tid < 256) {
    int base = (tid >= 128) ? 1 : 0;
    float s = red[base][tid] + red[base+2][tid] + red[base+4][tid] + red[base+6][tid];
    atomicAdd(&esumsq[tid], s);
  }
}

// ---------------- BN stats -> scale/shift ----------------
__global__ void k_stats(const float* __restrict__ sum, const float* __restrict__ sumsq,
                        const float* __restrict__ g, const float* __restrict__ beta,
                        float cnt, float* __restrict__ scale, float* __restrict__ shift) {
  int c = threadIdx.x;
  float m = sum[c] / cnt;
  float v = sumsq[c] / cnt - m*m;
  v = fmaxf(v, 0.f);
  float s = g[c] * rsqrtf(v + EPS_);
  scale[c] = s;
  shift[c] = beta[c] - m*s;
}

// ---------------- agg (packed f16) -> normalized bf16 (empty segments -> 0) ----------------
__global__ void k_aggnorm(const u32* __restrict__ aggh, const int* __restrict__ counts,
                          const float* __restrict__ scale, const float* __restrict__ shift,
                          u32* __restrict__ out) {
  int i = blockIdx.x * 256 + threadIdx.x;       // u32 pair index
  if (i >= M_NODE*C_/2) return;
  int n = i >> 7;
  int p = (i & 127) * 2;                        // channel base
  int cnt = counts[n];
  h2 hv = u2h2(aggh[i]);
  float v0 = (cnt > 0) ? fmaf((float)hv.x, scale[p],   shift[p])   : 0.f;
  float v1 = (cnt > 0) ? fmaf((float)hv.y, scale[p+1], shift[p+1]) : 0.f;
  out[i] = ((u32)f2bf(v0)) | (((u32)f2bf(v1)) << 16);
}

// ---------------- u GEMM: y=relu(agg@Wu+b); stats; store y (bf16) ----------------
__global__ __launch_bounds__(256)
void k_ugemm(const u16* __restrict__ A, const u16* __restrict__ WuT,
             const float* __restrict__ bu,
             u16* __restrict__ yu, float* __restrict__ usum, float* __restrict__ usumsq)
{
  __shared__ __align__(16) u16 As[128*32];
  __shared__ __align__(16) u16 Bs[128*32];
  const int t  = threadIdx.x;
  const int n0 = blockIdx.x * 128;
  const int mb = blockIdx.y * 128;

  int r0 = mb + (t >> 2);      if (r0 >= M_NODE) r0 = 0;
  int r1 = mb + 64 + (t >> 2); if (r1 >= M_NODE) r1 = 0;
  const int ak = (((t & 3) ^ ((t >> 3) & 3)) << 3);
  const u16* asrc0 = A + (size_t)r0 * C_ + ak;
  const u16* asrc1 = A + (size_t)r1 * C_ + ak;
  const u16* bsrc0 = WuT + (size_t)(n0 + (t >> 2)) * C_ + ak;
  const u16* bsrc1 = WuT + (size_t)(n0 + 64 + (t >> 2)) * C_ + ak;

  const f32x4 zero = {0.f, 0.f, 0.f, 0.f};
  f32x4 acc[4][4];
  #pragma unroll
  for (int m = 0; m < 4; m++)
    #pragma unroll
    for (int n = 0; n < 4; n++) acc[m][n] = zero;

  const int lane = t & 63, wave = t >> 6;
  const int wr = wave >> 1, wc = wave & 1;
  const int lr = lane & 15, lch = lane >> 4;
  const int swz = (lr >> 1) & 3;

  for (int kk = 0; kk < 8; kk++) {
    const int k0 = kk * 32;
    async16(&As[t*8],        asrc0 + k0);
    async16(&As[(t+256)*8],  asrc1 + k0);
    async16(&Bs[t*8],        bsrc0 + k0);
    async16(&Bs[(t+256)*8],  bsrc1 + k0);
    __syncthreads();
    bf16x8 a[4], b[4];
    #pragma unroll
    for (int m = 0; m < 4; m++)
      a[m] = *(const bf16x8*)&As[(wr*64 + m*16 + lr)*32 + ((lch ^ swz) << 3)];
    #pragma unroll
    for (int n = 0; n < 4; n++)
      b[n] = *(const bf16x8*)&Bs[(wc*64 + n*16 + lr)*32 + ((lch ^ swz) << 3)];
    #pragma unroll
    for (int m = 0; m < 4; m++)
      #pragma unroll
      for (int n = 0; n < 4; n++)
        acc[m][n] = __builtin_amdgcn_mfma_f32_16x16x32_bf16(a[m], b[n], acc[m][n], 0, 0, 0);
    __syncthreads();
  }

  int gc[4]; float bias[4];
  #pragma unroll
  for (int n = 0; n < 4; n++) { int c = n0 + wc*64 + n*16 + lr; gc[n] = c; bias[n] = bu[c]; }
  float psum[4] = {0.f,0.f,0.f,0.f};
  float psq [4] = {0.f,0.f,0.f,0.f};
  #pragma unroll
  for (int m = 0; m < 4; m++) {
    #pragma unroll
    for (int j = 0; j < 4; j++) {
      int r = mb + wr*64 + m*16 + lch*4 + j;
      bool valid = r < M_NODE;
      #pragma unroll
      for (int n = 0; n < 4; n++) {
        float y = fmaxf(acc[m][n][j] + bias[n], 0.f);
        if (valid) {
          psum[n] += y;
          psq[n]  += y*y;
          yu[(size_t)r * C_ + gc[n]] = f2bf(y);
        }
      }
    }
  }
  #pragma unroll
  for (int n = 0; n < 4; n++) {
    float s1 = psum[n], s2 = psq[n];
    s1 += __shfl_xor(s1, 16, 64);  s2 += __shfl_xor(s2, 16, 64);
    s1 += __shfl_xor(s1, 32, 64);  s2 += __shfl_xor(s2, 32, 64);
    if (lch == 0) { atomicAdd(&usum[gc[n]], s1); atomicAdd(&usumsq[gc[n]], s2); }
  }
}

// -------- final: BN affine + residual (bf16 vf) + transpose to [B][C][N] --------
__global__ void k_final(const u16* __restrict__ yu, const u16* __restrict__ vf,
                        const float* __restrict__ scale, const float* __restrict__ shift,
                        float* __restrict__ out) {
  __shared__ float tile[32][33];
  int tx = threadIdx.x & 31, ty = threadIdx.x >> 5;
  int b = blockIdx.z, c0 = blockIdx.y * 32, n0 = blockIdx.x * 32;
  #pragma unroll
  for (int i = 0; i < 4; i++) {
    int n = n0 + ty + i*8, c = c0 + tx;
    float v = 0.f;
    if (n < N_) {
      size_t idx = ((size_t)(b*N_ + n))*C_ + c;
      v = bf2f(yu[idx]) * scale[c] + shift[c] + bf2f(vf[idx]);
    }
    tile[ty + i*8][tx] = v;
  }
  __syncthreads();
  int n = n0 + tx;
  if (n < N_) {
    #pragma unroll
    for (int i = 0; i < 4; i++) {
      int c = c0 + ty + i*8;
      out[((size_t)(b*C_ + c))*N_ + n] = tile[tx][ty + i*8];
    }
  }
}

extern "C" void kernel_launch(void* const* d_in, const int* in_sizes, int n_in,
                              void* d_out, int out_size, void* d_ws, size_t ws_size,
                              hipStream_t stream) {
  const float* xyz  = (const float*)d_in[0];
  const float* feat = (const float*)d_in[1];
  const int*   edges= (const int*)  d_in[2];
  const float* We   = (const float*)d_in[3];
  const float* be   = (const float*)d_in[4];
  const float* ge   = (const float*)d_in[5];
  const float* bte  = (const float*)d_in[6];
  const float* Wu   = (const float*)d_in[7];
  const float* bu   = (const float*)d_in[8];
  const float* gu   = (const float*)d_in[9];
  const float* btu  = (const float*)d_in[10];
  float* out = (float*)d_out;

  char* w = (char*)d_ws;
  size_t off = 0;
  auto carve = [&](size_t bytes) -> void* {
    void* p = w + off;
    off = (off + bytes + 511) & ~(size_t)511;
    return p;
  };
  u16*  vf       = (u16*) carve((size_t)M_NODE*C_*2);       // 10.24 MB
  u16*  WeT      = (u16*) carve((size_t)C_*C_*2);
  u16*  WuT      = (u16*) carve((size_t)C_*C_*2);
  u16*  zh       = (u16*) carve((size_t)M_NODE*C_*2);       // 10.24 MB (fp16)
  uint2* ed      = (uint2*)carve((size_t)ED_CAP*8);         // 2.9 MB
  int*  counts   = (int*) carve((size_t)M_NODE*4);
  int*  offs     = (int*) carve((size_t)(M_NODE+1)*4);
  int*  cursor   = (int*) carve((size_t)M_NODE*4);
  u32*  nodeInfo = (u32*) carve((size_t)(M_NODE+2)*4);
  int*  waveStart= (int*) carve((size_t)(NW_+1)*4);
  u32*  aggh     = (u32*) carve((size_t)M_NODE*128*4);      // 10.24 MB (packed f16)
  u32*  aggnorm  = (u32*) carve((size_t)M_NODE*C_*2);       // 10.24 MB (bf16)
  u16*  yu       = (u16*) carve((size_t)M_NODE*C_*2);       // 10.24 MB (bf16)
  float* stats   = (float*)carve(2048*4);
  float* esum = stats,        *esumsq = stats + 256;
  float* usum = stats + 512,  *usumsq = stats + 768;
  float* scale_e = stats + 1024, *shift_e = stats + 1280;
  float* scale_u = stats + 1536, *shift_u = stats + 1792;

  k_init<<<dim3((M_NODE + 255)/256), 256, 0, stream>>>(counts, stats);
  k_transpose_feat<<<dim3((N_+31)/32, C_/32, B_), 256, 0, stream>>>(feat, vf);
  k_transpose_w<<<dim3(C_/32, C_/32, 2), 256, 0, stream>>>(We, Wu, WeT, WuT);
  k_hist<<<dim3((M_EDGE + 255)/256), 256, 0, stream>>>(edges, counts);
  k_scan<<<1, 1024, 0, stream>>>(counts, offs, cursor);
  k_scatter<<<dim3((M_EDGE + 255)/256), 256, 0, stream>>>(edges, xyz, cursor, ed);
  k_pad<<<dim3((M_NODE + 255)/256), 256, 0, stream>>>(offs, counts, ed, nodeInfo, waveStart);
  k_zgemm<<<dim3(2, (M_NODE + 127)/128), 256, 0, stream>>>(vf, WeT, be, zh);
  k_agg<<<dim3(NW_/4), 512, 0, stream>>>(zh, ed, offs, nodeInfo, waveStart,
                                         We, ge, aggh, esum, esumsq);
  k_stats<<<1, 256, 0, stream>>>(esum, esumsq, ge, bte, (float)M_EDGE, scale_e, shift_e);
  k_aggnorm<<<dim3(M_NODE*C_/512), 256, 0, stream>>>(aggh, counts, scale_e, shift_e, aggnorm);
  k_ugemm<<<dim3(2, (M_NODE + 127)/128), 256, 0, stream>>>(
      (const u16*)aggnorm, WuT, bu, yu, usum, usumsq);
  k_stats<<<1, 256, 0, stream>>>(usum, usumsq, gu, btu, (float)M_NODE, scale_u, shift_u);
  k_final<<<dim3((N_+31)/32, C_/32, B_), 256, 0, stream>>>(yu, vf, scale_u, shift_u, out);
}